// Round 1
// 751.816 us; speedup vs baseline: 1.0596x; 1.0596x over previous
//
#include <hip/hip_runtime.h>
#include <hip/hip_bf16.h>

typedef __attribute__((ext_vector_type(8))) __bf16 bf16x8;
typedef __attribute__((ext_vector_type(4))) float f32x4;

#define AVG_DEG_LOG 2.833213344056216f

__device__ __forceinline__ unsigned short f2bf(float f) {
  union { float f; unsigned int u; } a; a.f = f;
  unsigned int r = a.u + 0x7FFFu + ((a.u >> 16) & 1u);
  return (unsigned short)(r >> 16);
}

__device__ __forceinline__ uint2 pack4(f32x4 a) {
  uint2 u;
  u.x = (unsigned)f2bf(a[0]) | ((unsigned)f2bf(a[1]) << 16);
  u.y = (unsigned)f2bf(a[2]) | ((unsigned)f2bf(a[3]) << 16);
  return u;
}

// ---------------- fused histogram + W fp32->bf16 ----------------
__global__ void hist_wconv_kernel(const int* __restrict__ idx, int* __restrict__ cnt, int E,
                                  int hb, const float* __restrict__ W,
                                  unsigned short* __restrict__ Wb, int n4) {
  int b = blockIdx.x;
  if (b < hb) {
    int i = b * 256 + threadIdx.x;
    if (i < E) atomicAdd(&cnt[idx[i]], 1);
  } else {
    int i = (b - hb) * 256 + threadIdx.x;
    if (i < n4) {
      float4 v = ((const float4*)W)[i];
      ushort4 o;
      o.x = f2bf(v.x); o.y = f2bf(v.y); o.z = f2bf(v.z); o.w = f2bf(v.w);
      ((ushort4*)Wb)[i] = o;
    }
  }
}

// ---------------- exclusive scan (single block) ----------------
__global__ __launch_bounds__(1024) void scan_kernel(const int* __restrict__ cnt,
                                                    int* __restrict__ offsets, int N) {
  __shared__ int partial[1024];
  int t = threadIdx.x;
  int CH = (N + 1023) >> 10;
  int base = t * CH;
  int s = 0;
  for (int i = 0; i < CH; ++i) { int id = base + i; if (id < N) s += cnt[id]; }
  partial[t] = s;
  __syncthreads();
  int val = s;
  for (int off = 1; off < 1024; off <<= 1) {
    int add = (t >= off) ? partial[t - off] : 0;
    __syncthreads();
    val += add;
    partial[t] = val;
    __syncthreads();
  }
  int run = val - s;  // exclusive prefix of this thread's chunk
  for (int i = 0; i < CH; ++i) {
    int id = base + i;
    if (id < N) { offsets[id] = run; run += cnt[id]; }
  }
  if (t == 1023) offsets[N] = run;
}

// ---------------- scatter edge ids ----------------
__global__ void scatter_kernel(const int* __restrict__ idx, const int* __restrict__ offsets,
                               int* __restrict__ cursor, int* __restrict__ edge_ids, int E) {
  int i = blockIdx.x * blockDim.x + threadIdx.x;
  if (i < E) {
    int n = idx[i];
    int p = atomicAdd(&cursor[n], 1);
    edge_ids[offsets[n] + p] = i;
  }
}

// ---------------- per-node aggregation: one wave per node, v2 ----------------
// Wave split into two 32-lane halves; each half covers the full 128-feature row
// as float4 (16B/lane); halves take adjacent edges; unroll x4 => 8 rows (4KB)
// of independent loads in flight per wave.
__global__ __launch_bounds__(256) void agg_kernel(const float* __restrict__ x,
    const int* __restrict__ edge_ids, const int* __restrict__ offsets,
    unsigned short* __restrict__ agg4, float* __restrict__ amp, float* __restrict__ att, int Nn) {
  int wid = blockIdx.x * 4 + (threadIdx.x >> 6);
  if (wid >= Nn) return;
  int lane = threadIdx.x & 63;
  int half = lane >> 5;
  int fh = (lane & 31) * 4;
  int offs = offsets[wid];
  int deg = offsets[wid + 1] - offs;
  f32x4 s = {0.f, 0.f, 0.f, 0.f}, q = {0.f, 0.f, 0.f, 0.f};
  f32x4 mn = {INFINITY, INFINITY, INFINITY, INFINITY};
  f32x4 mx = {-INFINITY, -INFINITY, -INFINITY, -INFINITY};
  const float* xb = x + fh;
  for (int i = 0; i < deg; i += 64) {
    int myid = 0;
    if (i + lane < deg) myid = edge_ids[offs + i + lane];
    int c = deg - i; if (c > 64) c = 64;
    int ii = 0;
    for (; ii + 8 <= c; ii += 8) {
      int e0 = __shfl(myid, ii + half, 64);
      int e1 = __shfl(myid, ii + 2 + half, 64);
      int e2 = __shfl(myid, ii + 4 + half, 64);
      int e3 = __shfl(myid, ii + 6 + half, 64);
      f32x4 v0 = __builtin_nontemporal_load((const f32x4*)(xb + (size_t)e0 * 128));
      f32x4 v1 = __builtin_nontemporal_load((const f32x4*)(xb + (size_t)e1 * 128));
      f32x4 v2 = __builtin_nontemporal_load((const f32x4*)(xb + (size_t)e2 * 128));
      f32x4 v3 = __builtin_nontemporal_load((const f32x4*)(xb + (size_t)e3 * 128));
#pragma unroll
      for (int j = 0; j < 4; ++j) {
        s[j] += v0[j]; q[j] += v0[j] * v0[j]; mn[j] = fminf(mn[j], v0[j]); mx[j] = fmaxf(mx[j], v0[j]);
        s[j] += v1[j]; q[j] += v1[j] * v1[j]; mn[j] = fminf(mn[j], v1[j]); mx[j] = fmaxf(mx[j], v1[j]);
        s[j] += v2[j]; q[j] += v2[j] * v2[j]; mn[j] = fminf(mn[j], v2[j]); mx[j] = fmaxf(mx[j], v2[j]);
        s[j] += v3[j]; q[j] += v3[j] * v3[j]; mn[j] = fminf(mn[j], v3[j]); mx[j] = fmaxf(mx[j], v3[j]);
      }
    }
    for (; ii < c; ii += 2) {
      int p = ii + half;
      bool valid = p < c;
      int e = __shfl(myid, valid ? p : c - 1, 64);
      f32x4 v = __builtin_nontemporal_load((const f32x4*)(xb + (size_t)e * 128));
      if (valid) {
#pragma unroll
        for (int j = 0; j < 4; ++j) {
          s[j] += v[j]; q[j] += v[j] * v[j]; mn[j] = fminf(mn[j], v[j]); mx[j] = fmaxf(mx[j], v[j]);
        }
      }
    }
  }
  // combine the two halves (each handled alternating edges)
#pragma unroll
  for (int j = 0; j < 4; ++j) {
    s[j] += __shfl_xor(s[j], 32, 64);
    q[j] += __shfl_xor(q[j], 32, 64);
    mn[j] = fminf(mn[j], __shfl_xor(mn[j], 32, 64));
    mx[j] = fmaxf(mx[j], __shfl_xor(mx[j], 32, 64));
  }
  float cdeg = deg > 0 ? (float)deg : 1.0f;
  float inv = 1.0f / cdeg;
  f32x4 mean, sd;
#pragma unroll
  for (int j = 0; j < 4; ++j) {
    mean[j] = s[j] * inv;
    float var = q[j] * inv - mean[j] * mean[j];
    var = var > 0.f ? var : 0.f;
    sd[j] = sqrtf(var + 1e-5f);
  }
  if (deg == 0) {
#pragma unroll
    for (int j = 0; j < 4; ++j) { mn[j] = 0.f; mx[j] = 0.f; }
  }
  size_t rb = (size_t)wid * 512;
  if (half == 0) {
    *(uint2*)(agg4 + rb + fh)       = pack4(mean);
    *(uint2*)(agg4 + rb + 128 + fh) = pack4(mn);
  } else {
    *(uint2*)(agg4 + rb + 256 + fh) = pack4(mx);
    *(uint2*)(agg4 + rb + 384 + fh) = pack4(sd);
  }
  if (lane == 0) {
    float ld = logf(cdeg + 1.0f);
    amp[wid] = ld / AVG_DEG_LOG;
    att[wid] = AVG_DEG_LOG / ld;
  }
}

// ---------------- fused scaled GEMM: out = C0 + amp*C1 + att*C2 + b ----------------
// A = agg4 bf16 [Nn][512]; B = Wb bf16 [128][1536] (n-major); 3 K-groups of 512.
__global__ __launch_bounds__(256) void gemm_kernel(
    const unsigned short* __restrict__ agg4, const unsigned short* __restrict__ Wb,
    const float* __restrict__ amp, const float* __restrict__ att,
    const float* __restrict__ bias, float* __restrict__ out, int Nn) {
  __shared__ __align__(16) unsigned short As[64][40];        // 64 rows x 32 k (+8 pad)
  __shared__ __align__(16) unsigned short Bs[3][128][40];    // 3 groups x 128 n x 32 k (+8 pad)
  __shared__ float ampS[64], attS[64];
  int t = threadIdx.x;
  int m0 = blockIdx.x * 64;
  if (t < 64) {
    int n = m0 + t; if (n > Nn - 1) n = Nn - 1;
    ampS[t] = amp[n]; attS[t] = att[n];
  }
  int wave = t >> 6, lane = t & 63;
  int arow = lane & 15, quad = lane >> 4;
  f32x4 acc[3][8];
#pragma unroll
  for (int g = 0; g < 3; ++g)
#pragma unroll
    for (int c8 = 0; c8 < 8; ++c8) acc[g][c8] = (f32x4){0.f, 0.f, 0.f, 0.f};

  int ar = t >> 2;             // 0..63 row for A staging
  int akc = (t & 3) * 8;       // k offset for A staging
  int agr = m0 + ar; if (agr > Nn - 1) agr = Nn - 1;
  const unsigned short* aptr = agg4 + (size_t)agr * 512 + akc;

  for (int kk = 0; kk < 512; kk += 32) {
    __syncthreads();
    *(uint4*)&As[ar][akc] = *(const uint4*)(aptr + kk);
#pragma unroll
    for (int j = 0; j < 6; ++j) {
      int idx = t + j * 256;
      int g = idx >> 9;
      int rem = idx & 511;
      int n = rem >> 2;
      int kc = (rem & 3) * 8;
      *(uint4*)&Bs[g][n][kc] = *(const uint4*)(Wb + (size_t)n * 1536 + g * 512 + kk + kc);
    }
    __syncthreads();
    bf16x8 af = *(bf16x8*)&As[wave * 16 + arow][quad * 8];
#pragma unroll
    for (int g = 0; g < 3; ++g) {
#pragma unroll
      for (int c8 = 0; c8 < 8; ++c8) {
        bf16x8 bf = *(bf16x8*)&Bs[g][c8 * 16 + arow][quad * 8];
        acc[g][c8] = __builtin_amdgcn_mfma_f32_16x16x32_bf16(af, bf, acc[g][c8], 0, 0, 0);
      }
    }
  }
  // epilogue: C layout col=lane&15, row=quad*4+r
#pragma unroll
  for (int c8 = 0; c8 < 8; ++c8) {
    int col = c8 * 16 + arow;
    float bv = bias[col];
#pragma unroll
    for (int r = 0; r < 4; ++r) {
      int lrow = wave * 16 + quad * 4 + r;
      int n = m0 + lrow;
      if (n < Nn) {
        float o = acc[0][c8][r] + ampS[lrow] * acc[1][c8][r] + attS[lrow] * acc[2][c8][r] + bv;
        out[(size_t)n * 128 + col] = o;
      }
    }
  }
}

extern "C" void kernel_launch(void* const* d_in, const int* in_sizes, int n_in,
                              void* d_out, int out_size, void* d_ws, size_t ws_size,
                              hipStream_t stream) {
  const float* x     = (const float*)d_in[0];
  const int*   index = (const int*)d_in[1];
  const float* W     = (const float*)d_in[2];
  const float* bias  = (const float*)d_in[3];
  int E  = in_sizes[1];
  int Nn = out_size / 128;
  float* out = (float*)d_out;

  char* ws = (char*)d_ws;
  size_t off = 0;
  int* cnt     = (int*)(ws + off); off += (size_t)Nn * 4;
  int* cursor  = (int*)(ws + off); off += (size_t)Nn * 4;
  int* offsets = (int*)(ws + off); off += (size_t)(Nn + 1) * 4;
  off = (off + 255) & ~(size_t)255;
  int* edge_ids = (int*)(ws + off); off += (size_t)E * 4;
  off = (off + 255) & ~(size_t)255;
  unsigned short* agg4 = (unsigned short*)(ws + off); off += (size_t)Nn * 512 * 2;
  float* amp = (float*)(ws + off); off += (size_t)Nn * 4;
  float* att = (float*)(ws + off); off += (size_t)Nn * 4;
  off = (off + 255) & ~(size_t)255;
  unsigned short* Wb = (unsigned short*)(ws + off); off += (size_t)128 * 1536 * 2;

  // zero cnt + cursor (contiguous)
  hipMemsetAsync(ws, 0, (size_t)Nn * 8, stream);

  int eb = (E + 255) / 256;
  int n4 = 128 * 1536 / 4;
  int wb = (n4 + 255) / 256;
  hist_wconv_kernel<<<eb + wb, 256, 0, stream>>>(index, cnt, E, eb, W, Wb, n4);
  scan_kernel<<<1, 1024, 0, stream>>>(cnt, offsets, Nn);
  scatter_kernel<<<eb, 256, 0, stream>>>(index, offsets, cursor, edge_ids, E);
  agg_kernel<<<(Nn + 3) / 4, 256, 0, stream>>>(x, edge_ids, offsets, agg4, amp, att, Nn);
  gemm_kernel<<<(Nn + 63) / 64, 256, 0, stream>>>(agg4, Wb, amp, att, bias, out, Nn);
}